// Round 19
// baseline (73.120 us; speedup 1.0000x reference)
//
#include <hip/hip_runtime.h>

// MFMA fragment layouts (gfx950, 16x16 family, verified m89):
//   A-frag (M16,K32): lane l holds A[row=l&15][k=(l>>4)*8+e], e=0..7
//   B-frag (K32,N16): lane l holds B[k=(l>>4)*8+e][col=l&15]
//   C/D:              col=l&15, row=(l>>4)*4+reg
// h subtiled: hS[jt][et][16][16] f16 (512 B subtiles).
// ds_read_b64_tr_b16 (verified v6/v8): lane addr = subtile + lg*128 + ll*8;
// elem e = subtile[lg*4+e][ll] — the K16 PV A-frag.
//
// v19 = v18's flattened balance + v13's verified paired tile body.
// Unit space: 10 units/strip (9 pairs + tail tile 18), 190 total; wave w
// owns units [16w, min(16w+16,190)). Pairs: ONE defer-max softmax + ONE
// lgkmcnt(0) fence per 32 j (halves per-tile VALU/fence cost — VALU is the
// largest pipe at 38%). Tile 18 runs v18's single-tile body (tail padding).
// Segment merge: tail segment (r0>0) writes partial (m,lsum,acc28) to
// region[w-1] (v16-verified layout: lane*30 f32); head segment (r1<10)
// merges region[w] after ONE barrier (exact online-softmax combine);
// whole strips store directly.
// Geometry: 768 thr / 12 waves / grid 256 / NO reg bound (84 arch,
// spill-free). LDS 153.6 KB.

typedef _Float16 half8 __attribute__((ext_vector_type(8)));
typedef _Float16 half4 __attribute__((ext_vector_type(4)));
typedef float f32x4 __attribute__((ext_vector_type(4)));

constexpr int B_ = 256, N_ = 300, E_ = 100;
constexpr float NEGINF = -9e15f;
constexpr float PADV   = -3e38f;
constexpr float LOG2E  = 1.44269504088896f;

// LDS: hS [19][7][16][16] f16 (68096) | A16 [4][128] f16 @68096 (1024)
//      | 11 partial regions x 64 lanes x 30 f32 = 84480 B @69120
constexpr int PART_OFF  = 69120;
constexpr int LDS_BYTES = 69120 + 11 * 7680;   // 153600 <= 163840

#define TRD(dst, addr, off) \
  asm volatile("ds_read_b64_tr_b16 %0, %1 offset:" #off : "=v"(dst) : "v"(addr))
#define LGKM0 do { asm volatile("s_waitcnt lgkmcnt(0)" ::: "memory"); \
                   __builtin_amdgcn_sched_barrier(0); } while (0)

__global__ __launch_bounds__(768)
void gat_flash17(const float* __restrict__ H, const int* __restrict__ ADJ,
                 const float* __restrict__ A, float* __restrict__ OUT) {
  extern __shared__ char smraw[];
  _Float16* hS   = (_Float16*)smraw;
  _Float16* A16  = (_Float16*)(smraw + 68096);
  float*    part = (float*)(smraw + PART_OFF);

  const int b = blockIdx.x;
  const int tid = threadIdx.x;
  const int w = tid >> 6, lane = tid & 63;
  const int lg = lane >> 4, ll = lane & 15;

  const float* Hb  = H + (size_t)b * (N_ * E_);
  const int*   AJb = ADJ + (size_t)b * (N_ * N_);

  // ---------------- stage h into subtiled LDS (zero-padded) ----------------
  for (int u = tid; u < 304 * 14; u += 768) {
    const int j = u / 14, hr = u % 14;
    half8 v;
#pragma unroll
    for (int e = 0; e < 8; ++e) {
      const int d = hr * 8 + e;
      v[e] = (_Float16)((j < N_ && d < E_) ? Hb[j * E_ + d] : 0.f);
    }
    *(half8*)&hS[(((j >> 4) * 7 + (hr >> 1)) << 8) + ((j & 15) << 4) + ((hr & 1) << 3)] = v;
  }
  if (tid < 64) {
    const int k = tid >> 4, oct = tid & 15;
    half8 v;
#pragma unroll
    for (int e = 0; e < 8; ++e) {
      const int d = oct * 8 + e;
      v[e] = (_Float16)((d < E_) ? A[k * E_ + d] * LOG2E : 0.f);   // log2-domain
    }
    *(half8*)&A16[k * 128 + oct * 8] = v;
  }
  __syncthreads();

  const unsigned ldsbase = (unsigned)(size_t)(void*)hS;
  const unsigned trlane  = (unsigned)(ll * 8 + lg * 128);

  half8 g[3][4];
  half4 gt[4];
  float m, lsum;
  f32x4 acc[7];
  const int* ajrow = AJb;

  auto prep_strip = [&](int s) {
    const int irow = s * 16 + ll;
    const int irc  = irow < N_ ? irow : N_ - 1;
    ajrow = AJb + (size_t)irc * N_;
#pragma unroll
    for (int db = 0; db < 3; ++db) {
      const int doct = db * 4 + lg;
      const half8 hi = *(const half8*)&hS[((s * 7 + (doct >> 1)) << 8) + (ll << 4) + ((doct & 1) << 3)];
#pragma unroll
      for (int k = 0; k < 4; ++k)
        g[db][k] = hi * *(const half8*)&A16[k * 128 + doct * 8];
    }
    const half4 hit = *(const half4*)&hS[((s * 7 + 6) << 8) + (ll << 4) + lg * 4];
#pragma unroll
    for (int k = 0; k < 4; ++k)
      gt[k] = hit * *(const half4*)&A16[k * 128 + 96 + lg * 4];
    m = PADV; lsum = 0.f;
#pragma unroll
    for (int t = 0; t < 7; ++t) acc[t] = (f32x4){0.f, 0.f, 0.f, 0.f};
  };

  auto load_adj = [&](int jt) -> int4 {
    int jc = jt * 16 + lg * 4;
    if (jc > N_ - 4) jc = N_ - 4;
    return *(const int4*)(ajrow + jc);
  };

  // ---------------- paired tile body (v13-verified math) ----------------
  auto pair_body = [&](int jtA, int4 av0, int4 av1) {
    // scores tile A
    f32x4 c0 = {0.f, 0.f, 0.f, 0.f}, c1 = c0, c2 = c0, c3 = c0;
#pragma unroll
    for (int db = 0; db < 3; ++db) {
      const int doct = db * 4 + lg;
      const half8 aj = *(const half8*)&hS[((jtA * 7 + (doct >> 1)) << 8) + (ll << 4) + ((doct & 1) << 3)];
      c0 = __builtin_amdgcn_mfma_f32_16x16x32_f16(aj, g[db][0], c0, 0, 0, 0);
      c1 = __builtin_amdgcn_mfma_f32_16x16x32_f16(aj, g[db][1], c1, 0, 0, 0);
      c2 = __builtin_amdgcn_mfma_f32_16x16x32_f16(aj, g[db][2], c2, 0, 0, 0);
      c3 = __builtin_amdgcn_mfma_f32_16x16x32_f16(aj, g[db][3], c3, 0, 0, 0);
    }
    {
      const half4 ajt = *(const half4*)&hS[((jtA * 7 + 6) << 8) + (ll << 4) + lg * 4];
      c0 = __builtin_amdgcn_mfma_f32_16x16x16f16(ajt, gt[0], c0, 0, 0, 0);
      c1 = __builtin_amdgcn_mfma_f32_16x16x16f16(ajt, gt[1], c1, 0, 0, 0);
      c2 = __builtin_amdgcn_mfma_f32_16x16x16f16(ajt, gt[2], c2, 0, 0, 0);
      c3 = __builtin_amdgcn_mfma_f32_16x16x16f16(ajt, gt[3], c3, 0, 0, 0);
    }
    const int vaA[4] = {av0.x, av0.y, av0.z, av0.w};
    float svA[4];
#pragma unroll
    for (int r = 0; r < 4; ++r) {
      const float e = (vaA[r] == 1) ? c0[r] : (vaA[r] == 2) ? c1[r]
                     : (vaA[r] == 3) ? c2[r] : c3[r];
      svA[r] = (vaA[r] == 0) ? NEGINF : fmaxf(e, 0.2f * e);
    }
    // scores tile B (chain regs reused after svA extracted)
    const int jtB = jtA + 1;
    f32x4 d0 = {0.f, 0.f, 0.f, 0.f}, d1 = d0, d2 = d0, d3 = d0;
#pragma unroll
    for (int db = 0; db < 3; ++db) {
      const int doct = db * 4 + lg;
      const half8 aj = *(const half8*)&hS[((jtB * 7 + (doct >> 1)) << 8) + (ll << 4) + ((doct & 1) << 3)];
      d0 = __builtin_amdgcn_mfma_f32_16x16x32_f16(aj, g[db][0], d0, 0, 0, 0);
      d1 = __builtin_amdgcn_mfma_f32_16x16x32_f16(aj, g[db][1], d1, 0, 0, 0);
      d2 = __builtin_amdgcn_mfma_f32_16x16x32_f16(aj, g[db][2], d2, 0, 0, 0);
      d3 = __builtin_amdgcn_mfma_f32_16x16x32_f16(aj, g[db][3], d3, 0, 0, 0);
    }
    {
      const half4 ajt = *(const half4*)&hS[((jtB * 7 + 6) << 8) + (ll << 4) + lg * 4];
      d0 = __builtin_amdgcn_mfma_f32_16x16x16f16(ajt, gt[0], d0, 0, 0, 0);
      d1 = __builtin_amdgcn_mfma_f32_16x16x16f16(ajt, gt[1], d1, 0, 0, 0);
      d2 = __builtin_amdgcn_mfma_f32_16x16x16f16(ajt, gt[2], d2, 0, 0, 0);
      d3 = __builtin_amdgcn_mfma_f32_16x16x16f16(ajt, gt[3], d3, 0, 0, 0);
    }
    const int vaB[4] = {av1.x, av1.y, av1.z, av1.w};
    float svB[4];
#pragma unroll
    for (int r = 0; r < 4; ++r) {
      const float e = (vaB[r] == 1) ? d0[r] : (vaB[r] == 2) ? d1[r]
                     : (vaB[r] == 3) ? d2[r] : d3[r];
      svB[r] = (vaB[r] == 0) ? NEGINF : fmaxf(e, 0.2f * e);
    }

    // 14 tr reads; latency covered by softmax below
    const unsigned trbA = ldsbase + (unsigned)(jtA * 3584) + trlane;
    half4 hfA[7], hfB[7];
    TRD(hfA[0], trbA, 0);    TRD(hfA[1], trbA, 512);  TRD(hfA[2], trbA, 1024);
    TRD(hfA[3], trbA, 1536); TRD(hfA[4], trbA, 2048); TRD(hfA[5], trbA, 2560);
    TRD(hfA[6], trbA, 3072);
    TRD(hfB[0], trbA, 3584); TRD(hfB[1], trbA, 4096); TRD(hfB[2], trbA, 4608);
    TRD(hfB[3], trbA, 5120); TRD(hfB[4], trbA, 5632); TRD(hfB[5], trbA, 6144);
    TRD(hfB[6], trbA, 6656);

    // ONE deferred online-softmax update per 32 j
    const float lmax = fmaxf(fmaxf(fmaxf(svA[0], svA[1]), fmaxf(svA[2], svA[3])),
                             fmaxf(fmaxf(svB[0], svB[1]), fmaxf(svB[2], svB[3])));
    if (__any(lmax > m + 8.f)) {
      float tmax = fmaxf(lmax, __shfl_xor(lmax, 16));
      tmax = fmaxf(tmax, __shfl_xor(tmax, 32));
      const float nm = fmaxf(m, tmax);
      const float f = exp2f(m - nm);
      m = nm; lsum *= f;
#pragma unroll
      for (int t = 0; t < 7; ++t) {
        acc[t][0] *= f; acc[t][1] *= f; acc[t][2] *= f; acc[t][3] *= f;
      }
    }
    const float pA0 = exp2f(svA[0] - m), pA1 = exp2f(svA[1] - m);
    const float pA2 = exp2f(svA[2] - m), pA3 = exp2f(svA[3] - m);
    const float pB0 = exp2f(svB[0] - m), pB1 = exp2f(svB[1] - m);
    const float pB2 = exp2f(svB[2] - m), pB3 = exp2f(svB[3] - m);
    lsum += ((pA0 + pA1) + (pA2 + pA3)) + ((pB0 + pB1) + (pB2 + pB3));
    half4 pbA, pbB;
    pbA[0] = (_Float16)pA0; pbA[1] = (_Float16)pA1;
    pbA[2] = (_Float16)pA2; pbA[3] = (_Float16)pA3;
    pbB[0] = (_Float16)pB0; pbB[1] = (_Float16)pB1;
    pbB[2] = (_Float16)pB2; pbB[3] = (_Float16)pB3;

    LGKM0;   // one fence for all 14 tr reads (rule #18)
#pragma unroll
    for (int t = 0; t < 7; ++t) {
      acc[t] = __builtin_amdgcn_mfma_f32_16x16x16f16(hfA[t], pbA, acc[t], 0, 0, 0);
      acc[t] = __builtin_amdgcn_mfma_f32_16x16x16f16(hfB[t], pbB, acc[t], 0, 0, 0);
    }
  };

  // ---------------- single tile body (tile 18 only) ----------------
  auto tile_body = [&](int jt, int4 av, bool tail) {
    f32x4 c0 = {0.f, 0.f, 0.f, 0.f}, c1 = c0, c2 = c0, c3 = c0;
#pragma unroll
    for (int db = 0; db < 3; ++db) {
      const int doct = db * 4 + lg;
      const half8 aj = *(const half8*)&hS[((jt * 7 + (doct >> 1)) << 8) + (ll << 4) + ((doct & 1) << 3)];
      c0 = __builtin_amdgcn_mfma_f32_16x16x32_f16(aj, g[db][0], c0, 0, 0, 0);
      c1 = __builtin_amdgcn_mfma_f32_16x16x32_f16(aj, g[db][1], c1, 0, 0, 0);
      c2 = __builtin_amdgcn_mfma_f32_16x16x32_f16(aj, g[db][2], c2, 0, 0, 0);
      c3 = __builtin_amdgcn_mfma_f32_16x16x32_f16(aj, g[db][3], c3, 0, 0, 0);
    }
    {
      const half4 ajt = *(const half4*)&hS[((jt * 7 + 6) << 8) + (ll << 4) + lg * 4];
      c0 = __builtin_amdgcn_mfma_f32_16x16x16f16(ajt, gt[0], c0, 0, 0, 0);
      c1 = __builtin_amdgcn_mfma_f32_16x16x16f16(ajt, gt[1], c1, 0, 0, 0);
      c2 = __builtin_amdgcn_mfma_f32_16x16x16f16(ajt, gt[2], c2, 0, 0, 0);
      c3 = __builtin_amdgcn_mfma_f32_16x16x16f16(ajt, gt[3], c3, 0, 0, 0);
    }
    const int va[4] = {av.x, av.y, av.z, av.w};
    float sv[4];
#pragma unroll
    for (int r = 0; r < 4; ++r) {
      const float e = (va[r] == 1) ? c0[r] : (va[r] == 2) ? c1[r]
                     : (va[r] == 3) ? c2[r] : c3[r];
      sv[r] = (va[r] == 0) ? NEGINF : fmaxf(e, 0.2f * e);
    }
    if (tail && lg == 3) { sv[0] = PADV; sv[1] = PADV; sv[2] = PADV; sv[3] = PADV; }

    const unsigned trb = ldsbase + (unsigned)(jt * 3584) + trlane;
    half4 tr[7];
    TRD(tr[0], trb, 0);    TRD(tr[1], trb, 512);  TRD(tr[2], trb, 1024);
    TRD(tr[3], trb, 1536); TRD(tr[4], trb, 2048); TRD(tr[5], trb, 2560);
    TRD(tr[6], trb, 3072);

    const float lmax = fmaxf(fmaxf(sv[0], sv[1]), fmaxf(sv[2], sv[3]));
    if (__any(lmax > m + 8.f)) {
      float tmax = fmaxf(lmax, __shfl_xor(lmax, 16));
      tmax = fmaxf(tmax, __shfl_xor(tmax, 32));
      const float nm = fmaxf(m, tmax);
      const float f = exp2f(m - nm);
      m = nm; lsum *= f;
#pragma unroll
      for (int t = 0; t < 7; ++t) {
        acc[t][0] *= f; acc[t][1] *= f; acc[t][2] *= f; acc[t][3] *= f;
      }
    }
    const float p0 = exp2f(sv[0] - m), p1 = exp2f(sv[1] - m);
    const float p2 = exp2f(sv[2] - m), p3 = exp2f(sv[3] - m);
    lsum += (p0 + p1) + (p2 + p3);
    half4 pb;
    pb[0] = (_Float16)p0; pb[1] = (_Float16)p1;
    pb[2] = (_Float16)p2; pb[3] = (_Float16)p3;

    LGKM0;
#pragma unroll
    for (int t = 0; t < 7; ++t)
      acc[t] = __builtin_amdgcn_mfma_f32_16x16x16f16(tr[t], pb, acc[t], 0, 0, 0);
  };

  auto store_rows = [&](int s) {
    float ls = lsum;
    ls += __shfl_xor(ls, 16);
    ls += __shfl_xor(ls, 32);
    const float rv = 1.f / ls;
    const int irow = s * 16 + ll;
    if (irow < N_) {
      float* orow = OUT + ((size_t)b * N_ + irow) * E_;
#pragma unroll
      for (int t = 0; t < 7; ++t) {
        const int e0 = t * 16 + lg * 4;
        if (e0 < E_) {
          f32x4 o = acc[t];
          o[0] *= rv; o[1] *= rv; o[2] *= rv; o[3] *= rv;
          *(f32x4*)&orow[e0] = o;
        }
      }
    }
  };

  // ====== flattened PAIR-unit space: 10 units/strip (9 pairs + tail) =======
  int u = 16 * w;
  const int u1 = (u + 16 < 190) ? u + 16 : 190;
  bool held = false;
  int s_held = 0;

  while (u < u1) {
    const int s  = u / 10, r0 = u - 10 * s;
    const int r1 = (10 < r0 + (u1 - u)) ? 10 : (r0 + (u1 - u));
    prep_strip(s);
    int t = (r0 < 9) ? 2 * r0 : 18;
    const int tEnd = (r1 == 10) ? 19 : ((r1 < 9) ? 2 * r1 : 18);

    if (t + 1 < tEnd) {
      int4 av0 = load_adj(t), av1 = load_adj(t + 1);
      while (t + 1 < tEnd) {
        const int4 nv0 = load_adj(t + 2), nv1 = load_adj(t + 3);  // clamped
        pair_body(t, av0, av1);
        av0 = nv0; av1 = nv1;
        t += 2;
      }
    }
    if (t < tEnd) {                      // t == 18: tail tile
      tile_body(18, load_adj(18), true);
    }

    if (r0 > 0) {
      float* dst = part + (size_t)(w - 1) * 1920 + lane * 30;
#pragma unroll
      for (int tt = 0; tt < 7; ++tt) {
        dst[4 * tt + 0] = acc[tt][0]; dst[4 * tt + 1] = acc[tt][1];
        dst[4 * tt + 2] = acc[tt][2]; dst[4 * tt + 3] = acc[tt][3];
      }
      dst[28] = m; dst[29] = lsum;
    } else if (r1 < 10) {
      held = true; s_held = s;
    } else {
      store_rows(s);
    }
    u += r1 - r0;
  }

  __syncthreads();

  if (held) {
    const float* src = part + (size_t)w * 1920 + lane * 30;
    const float mq = src[28], lq = src[29];
    const float M  = fmaxf(m, mq);
    const float f0 = exp2f(m - M), f1 = exp2f(mq - M);
    m = M;
    lsum = lsum * f0 + lq * f1;
#pragma unroll
    for (int t = 0; t < 7; ++t) {
      acc[t][0] = acc[t][0] * f0 + src[4 * t + 0] * f1;
      acc[t][1] = acc[t][1] * f0 + src[4 * t + 1] * f1;
      acc[t][2] = acc[t][2] * f0 + src[4 * t + 2] * f1;
      acc[t][3] = acc[t][3] * f0 + src[4 * t + 3] * f1;
    }
    store_rows(s_held);
  }
}

extern "C" void kernel_launch(void* const* d_in, const int* in_sizes, int n_in,
                              void* d_out, int out_size, void* d_ws, size_t ws_size,
                              hipStream_t stream) {
  const float* H  = (const float*)d_in[0];
  const int*   AJ = (const int*)d_in[1];
  const float* A  = (const float*)d_in[2];
  float* OUT = (float*)d_out;

  (void)hipFuncSetAttribute(reinterpret_cast<const void*>(gat_flash17),
                            hipFuncAttributeMaxDynamicSharedMemorySize,
                            LDS_BYTES);
  gat_flash17<<<B_, 768, LDS_BYTES, stream>>>(H, AJ, A, OUT);
}

// Round 20
// 67.520 us; speedup vs baseline: 1.0829x; 1.0829x over previous
//
#include <hip/hip_runtime.h>

// MFMA fragment layouts (gfx950, 16x16 family, verified m89):
//   A-frag (M16,K32): lane l holds A[row=l&15][k=(l>>4)*8+e], e=0..7
//   B-frag (K32,N16): lane l holds B[k=(l>>4)*8+e][col=l&15]
//   C/D:              col=l&15, row=(l>>4)*4+reg
// h subtiled: hS[jt][et][16][16] f16 (512 B subtiles).
// ds_read_b64_tr_b16 (verified v6/v8): lane addr = subtile + lg*128 + ll*8;
// elem e = subtile[lg*4+e][ll] — the K16 PV A-frag.
//
// v20 = v18 (best: 67.7 us) + T5 s_setprio(1) around both MFMA clusters.
// v18: flattened balance — wave w owns units [30w, 30(w+1)) of the 19x19
// (strip,tile) space; tail segment (j0>0) writes partial (m,lsum,acc28) to
// region[w-1] (verified layout lane*30 f32); head segment (j1<19) merges
// region[w] after ONE barrier (exact online-softmax combine); whole strips
// store directly. Geometry: 768 thr / 12 waves / grid 256, NO reg bound
// (84 arch + 48 acc, spill-free). LDS 153.6 KB.
// T5 rationale: 3 waves/SIMD at desynchronized phases (no main-loop
// barriers) = the attn-like regime where setprio measured +4-7% (m191);
// zero register cost, body otherwise byte-identical to v18.

typedef _Float16 half8 __attribute__((ext_vector_type(8)));
typedef _Float16 half4 __attribute__((ext_vector_type(4)));
typedef float f32x4 __attribute__((ext_vector_type(4)));

constexpr int B_ = 256, N_ = 300, E_ = 100;
constexpr float NEGINF = -9e15f;
constexpr float PADV   = -3e38f;
constexpr float LOG2E  = 1.44269504088896f;

// LDS: hS [19][7][16][16] f16 (68096) | A16 [4][128] f16 @68096 (1024)
//      | 11 partial regions x 64 lanes x 30 f32 = 84480 B @69120
constexpr int PART_OFF  = 69120;
constexpr int LDS_BYTES = 69120 + 11 * 7680;   // 153600 <= 163840

#define TRD(dst, addr, off) \
  asm volatile("ds_read_b64_tr_b16 %0, %1 offset:" #off : "=v"(dst) : "v"(addr))
#define LGKM0 do { asm volatile("s_waitcnt lgkmcnt(0)" ::: "memory"); \
                   __builtin_amdgcn_sched_barrier(0); } while (0)

__global__ __launch_bounds__(768)
void gat_flash18(const float* __restrict__ H, const int* __restrict__ ADJ,
                 const float* __restrict__ A, float* __restrict__ OUT) {
  extern __shared__ char smraw[];
  _Float16* hS   = (_Float16*)smraw;
  _Float16* A16  = (_Float16*)(smraw + 68096);
  float*    part = (float*)(smraw + PART_OFF);

  const int b = blockIdx.x;
  const int tid = threadIdx.x;
  const int w = tid >> 6, lane = tid & 63;
  const int lg = lane >> 4, ll = lane & 15;

  const float* Hb  = H + (size_t)b * (N_ * E_);
  const int*   AJb = ADJ + (size_t)b * (N_ * N_);

  // ---------------- stage h into subtiled LDS (zero-padded) ----------------
  for (int u = tid; u < 304 * 14; u += 768) {
    const int j = u / 14, hr = u % 14;
    half8 v;
#pragma unroll
    for (int e = 0; e < 8; ++e) {
      const int d = hr * 8 + e;
      v[e] = (_Float16)((j < N_ && d < E_) ? Hb[j * E_ + d] : 0.f);
    }
    *(half8*)&hS[(((j >> 4) * 7 + (hr >> 1)) << 8) + ((j & 15) << 4) + ((hr & 1) << 3)] = v;
  }
  if (tid < 64) {
    const int k = tid >> 4, oct = tid & 15;
    half8 v;
#pragma unroll
    for (int e = 0; e < 8; ++e) {
      const int d = oct * 8 + e;
      v[e] = (_Float16)((d < E_) ? A[k * E_ + d] * LOG2E : 0.f);   // log2-domain
    }
    *(half8*)&A16[k * 128 + oct * 8] = v;
  }
  __syncthreads();

  const unsigned ldsbase = (unsigned)(size_t)(void*)hS;
  const unsigned trlane  = (unsigned)(ll * 8 + lg * 128);

  half8 g[3][4];
  half4 gt[4];
  float m, lsum;
  f32x4 acc[7];
  const int* ajrow = AJb;

  auto prep_strip = [&](int s) {
    const int irow = s * 16 + ll;
    const int irc  = irow < N_ ? irow : N_ - 1;
    ajrow = AJb + (size_t)irc * N_;
#pragma unroll
    for (int db = 0; db < 3; ++db) {
      const int doct = db * 4 + lg;
      const half8 hi = *(const half8*)&hS[((s * 7 + (doct >> 1)) << 8) + (ll << 4) + ((doct & 1) << 3)];
#pragma unroll
      for (int k = 0; k < 4; ++k)
        g[db][k] = hi * *(const half8*)&A16[k * 128 + doct * 8];
    }
    const half4 hit = *(const half4*)&hS[((s * 7 + 6) << 8) + (ll << 4) + lg * 4];
#pragma unroll
    for (int k = 0; k < 4; ++k)
      gt[k] = hit * *(const half4*)&A16[k * 128 + 96 + lg * 4];
    m = PADV; lsum = 0.f;
#pragma unroll
    for (int t = 0; t < 7; ++t) acc[t] = (f32x4){0.f, 0.f, 0.f, 0.f};
  };

  auto load_adj = [&](int jt) -> int4 {
    int jc = jt * 16 + lg * 4;
    if (jc > N_ - 4) jc = N_ - 4;
    return *(const int4*)(ajrow + jc);
  };

  auto tile_body = [&](int jt, int4 av, bool tail) {
    f32x4 c0 = {0.f, 0.f, 0.f, 0.f}, c1 = c0, c2 = c0, c3 = c0;
    __builtin_amdgcn_s_setprio(1);
#pragma unroll
    for (int db = 0; db < 3; ++db) {
      const int doct = db * 4 + lg;
      const half8 aj = *(const half8*)&hS[((jt * 7 + (doct >> 1)) << 8) + (ll << 4) + ((doct & 1) << 3)];
      c0 = __builtin_amdgcn_mfma_f32_16x16x32_f16(aj, g[db][0], c0, 0, 0, 0);
      c1 = __builtin_amdgcn_mfma_f32_16x16x32_f16(aj, g[db][1], c1, 0, 0, 0);
      c2 = __builtin_amdgcn_mfma_f32_16x16x32_f16(aj, g[db][2], c2, 0, 0, 0);
      c3 = __builtin_amdgcn_mfma_f32_16x16x32_f16(aj, g[db][3], c3, 0, 0, 0);
    }
    {
      const half4 ajt = *(const half4*)&hS[((jt * 7 + 6) << 8) + (ll << 4) + lg * 4];
      c0 = __builtin_amdgcn_mfma_f32_16x16x16f16(ajt, gt[0], c0, 0, 0, 0);
      c1 = __builtin_amdgcn_mfma_f32_16x16x16f16(ajt, gt[1], c1, 0, 0, 0);
      c2 = __builtin_amdgcn_mfma_f32_16x16x16f16(ajt, gt[2], c2, 0, 0, 0);
      c3 = __builtin_amdgcn_mfma_f32_16x16x16f16(ajt, gt[3], c3, 0, 0, 0);
    }
    __builtin_amdgcn_s_setprio(0);
    const int va[4] = {av.x, av.y, av.z, av.w};
    float sv[4];
#pragma unroll
    for (int r = 0; r < 4; ++r) {
      const float e = (va[r] == 1) ? c0[r] : (va[r] == 2) ? c1[r]
                     : (va[r] == 3) ? c2[r] : c3[r];
      sv[r] = (va[r] == 0) ? NEGINF : fmaxf(e, 0.2f * e);
    }
    if (tail && lg == 3) { sv[0] = PADV; sv[1] = PADV; sv[2] = PADV; sv[3] = PADV; }

    const unsigned trb = ldsbase + (unsigned)(jt * 3584) + trlane;
    half4 tr[7];
    TRD(tr[0], trb, 0);    TRD(tr[1], trb, 512);  TRD(tr[2], trb, 1024);
    TRD(tr[3], trb, 1536); TRD(tr[4], trb, 2048); TRD(tr[5], trb, 2560);
    TRD(tr[6], trb, 3072);

    const float lmax = fmaxf(fmaxf(sv[0], sv[1]), fmaxf(sv[2], sv[3]));
    if (__any(lmax > m + 8.f)) {
      float tmax = fmaxf(lmax, __shfl_xor(lmax, 16));
      tmax = fmaxf(tmax, __shfl_xor(tmax, 32));
      const float nm = fmaxf(m, tmax);
      const float f = exp2f(m - nm);
      m = nm; lsum *= f;
#pragma unroll
      for (int t = 0; t < 7; ++t) {
        acc[t][0] *= f; acc[t][1] *= f; acc[t][2] *= f; acc[t][3] *= f;
      }
    }
    const float p0 = exp2f(sv[0] - m), p1 = exp2f(sv[1] - m);
    const float p2 = exp2f(sv[2] - m), p3 = exp2f(sv[3] - m);
    lsum += (p0 + p1) + (p2 + p3);
    half4 pb;
    pb[0] = (_Float16)p0; pb[1] = (_Float16)p1;
    pb[2] = (_Float16)p2; pb[3] = (_Float16)p3;

    LGKM0;   // rule #18
    __builtin_amdgcn_s_setprio(1);
#pragma unroll
    for (int t = 0; t < 7; ++t)
      acc[t] = __builtin_amdgcn_mfma_f32_16x16x16f16(tr[t], pb, acc[t], 0, 0, 0);
    __builtin_amdgcn_s_setprio(0);
  };

  auto store_rows = [&](int s) {
    float ls = lsum;
    ls += __shfl_xor(ls, 16);
    ls += __shfl_xor(ls, 32);
    const float rv = 1.f / ls;
    const int irow = s * 16 + ll;
    if (irow < N_) {
      float* orow = OUT + ((size_t)b * N_ + irow) * E_;
#pragma unroll
      for (int t = 0; t < 7; ++t) {
        const int e0 = t * 16 + lg * 4;
        if (e0 < E_) {
          f32x4 o = acc[t];
          o[0] *= rv; o[1] *= rv; o[2] *= rv; o[3] *= rv;
          *(f32x4*)&orow[e0] = o;
        }
      }
    }
  };

  // ============ flattened tile-space: wave w owns units [30w, u1) ==========
  int u = 30 * w;
  const int u1 = (w == 11) ? 361 : (u + 30);
  bool held = false;
  int s_held = 0;

  while (u < u1) {
    const int s  = u / 19;
    const int j0 = u - 19 * s;
    const int j1 = (19 < j0 + (u1 - u)) ? 19 : (j0 + (u1 - u));
    prep_strip(s);
    int4 av = load_adj(j0);
    for (int jt = j0; jt < j1; ++jt) {
      const int4 nv = (jt + 1 < j1) ? load_adj(jt + 1) : av;
      tile_body(jt, av, jt == 18);
      av = nv;
    }
    if (j0 > 0) {
      // tail segment of a split strip -> write partial to region[w-1]
      float* dst = part + (size_t)(w - 1) * 1920 + lane * 30;
#pragma unroll
      for (int t = 0; t < 7; ++t) {
        dst[4 * t + 0] = acc[t][0]; dst[4 * t + 1] = acc[t][1];
        dst[4 * t + 2] = acc[t][2]; dst[4 * t + 3] = acc[t][3];
      }
      dst[28] = m; dst[29] = lsum;
    } else if (j1 < 19) {
      held = true; s_held = s;       // head segment: merge after barrier
    } else {
      store_rows(s);                 // whole strip
    }
    u += j1 - j0;
  }

  __syncthreads();

  if (held) {
    // merge region[w] (written by wave w+1's tail segment of s_held)
    const float* src = part + (size_t)w * 1920 + lane * 30;
    const float mq = src[28], lq = src[29];
    const float M  = fmaxf(m, mq);
    const float f0 = exp2f(m - M), f1 = exp2f(mq - M);
    m = M;
    lsum = lsum * f0 + lq * f1;
#pragma unroll
    for (int t = 0; t < 7; ++t) {
      acc[t][0] = acc[t][0] * f0 + src[4 * t + 0] * f1;
      acc[t][1] = acc[t][1] * f0 + src[4 * t + 1] * f1;
      acc[t][2] = acc[t][2] * f0 + src[4 * t + 2] * f1;
      acc[t][3] = acc[t][3] * f0 + src[4 * t + 3] * f1;
    }
    store_rows(s_held);
  }
}

extern "C" void kernel_launch(void* const* d_in, const int* in_sizes, int n_in,
                              void* d_out, int out_size, void* d_ws, size_t ws_size,
                              hipStream_t stream) {
  const float* H  = (const float*)d_in[0];
  const int*   AJ = (const int*)d_in[1];
  const float* A  = (const float*)d_in[2];
  float* OUT = (float*)d_out;

  (void)hipFuncSetAttribute(reinterpret_cast<const void*>(gat_flash18),
                            hipFuncAttributeMaxDynamicSharedMemorySize,
                            LDS_BYTES);
  gat_flash18<<<B_, 768, LDS_BYTES, stream>>>(H, AJ, A, OUT);
}